// Round 8
// baseline (197.552 us; speedup 1.0000x reference)
//
#include <hip/hip_runtime.h>

typedef __attribute__((ext_vector_type(8))) short short8;
typedef __attribute__((ext_vector_type(4))) short shortx4;
typedef __attribute__((ext_vector_type(4))) float floatx4;
typedef __attribute__((ext_vector_type(4))) _Float16 half4;

__device__ __forceinline__ short bf16_short(float f) {
    unsigned u = __builtin_bit_cast(unsigned, f);
    u = (u + 0x7fff + ((u >> 16) & 1)) >> 16;   // RNE, finite values only
    return (short)u;
}

__device__ __forceinline__ float fast_exp2(float x) {
#if __has_builtin(__builtin_amdgcn_exp2f)
    return __builtin_amdgcn_exp2f(x);
#else
    return __expf(x * 0.6931471805599453f);
#endif
}

// ---------------------------------------------------------------------------
// Kernel 1: relayout weights (fp32 -> bf16) for MFMA A-fragments.
// Wt layout: [tap(9)][cog(4)][chunk(16)][co(128)][j(8)]  (ci = chunk*8+j)
// Wot layout: [chunk(16)][co(128)][j(8)]
// ---------------------------------------------------------------------------
__global__ __launch_bounds__(256) void transform_w(
    const float* __restrict__ wi, const float* __restrict__ wq,
    const float* __restrict__ wo, short* __restrict__ Wt, short* __restrict__ Wot)
{
    int idx = blockIdx.x * 256 + threadIdx.x;
    if (idx < 589824) {
        int j  = idx & 7;
        int t1 = idx >> 3;
        int co = t1 & 127;
        int t2 = t1 >> 7;
        int chunk = t2 & 15;
        int t3 = t2 >> 4;
        int cog = t3 & 3;
        int tap = t3 >> 2;
        int ci = chunk * 8 + j;
        float v;
        if (cog == 0) v = wi[(co * 128 + ci) * 9 + tap];
        else          v = wq[((((cog - 1) * 128) + co) * 128 + ci) * 9 + tap];
        Wt[idx] = bf16_short(v);
    } else if (idx < 589824 + 16384) {
        int i2 = idx - 589824;
        int j  = i2 & 7;
        int co = (i2 >> 3) & 127;
        int chunk = i2 >> 10;
        int ci = chunk * 8 + j;
        Wot[i2] = bf16_short(wo[co * 128 + ci]);
    }
}

// ---------------------------------------------------------------------------
// Kernel 2: fused circular 3x3 convs (init 128ch + qkv 384ch) as implicit GEMM.
// Block = (y-row, cog, b). M=128 (co group), N=48 (cols of row y), K=1152.
// cog==0 -> d_out (fp32) ch 0..127
// cog==1 -> qT  f16 [bh][n][d] transposed (scaled 0.25*log2(e)), half4 stores
// cog==2 -> kT  f16 [bh][n][d] transposed, half4 stores
// cog==3 -> vbuf f16 [b][c][n] (d-major rows, as attn's V A-operand wants)
// The transposed writes exploit: C-regs r=0..3 are d=quad*4+r (contiguous).
// ---------------------------------------------------------------------------
__global__ __launch_bounds__(256) void conv_main(
    const float* __restrict__ x, const short* __restrict__ Wt,
    float* __restrict__ dout, _Float16* __restrict__ qT,
    _Float16* __restrict__ kT, _Float16* __restrict__ vbuf)
{
    const int y   = blockIdx.x;   // 0..47
    const int cog = blockIdx.y;   // 0..3
    const int b   = blockIdx.z;   // 0..3

    __shared__ short Xs[16 * 3 * 48 * 8];   // [(chunk*3+row)*48+col]*8+j
    __shared__ short Ws[16 * 128 * 8];      // [chunk][co][j]

    const int t = threadIdx.x;

    // Stage X rows y-1,y,y+1 (wrapped): 128ci x 3row x 48col, fp32 -> bf16
    {
        const float* xb = x + b * 128 * 2304;
        #pragma unroll 4
        for (int it = 0; it < 36; ++it) {
            int e   = it * 256 + t;          // 0..9215 column pairs
            int ci  = e / 72;
            int r   = e - ci * 72;
            int row = r / 24;
            int cp  = r - row * 24;
            int rowg = y + row - 1;
            rowg = (rowg < 0) ? rowg + 48 : (rowg >= 48 ? rowg - 48 : rowg);
            float2 v = *(const float2*)(xb + (ci * 48 + rowg) * 48 + cp * 2);
            int slot = ((ci >> 3) * 3 + row) * 48 + cp * 2;
            int j = ci & 7;
            Xs[slot * 8 + j]       = bf16_short(v.x);
            Xs[(slot + 1) * 8 + j] = bf16_short(v.y);
        }
    }

    const int wave = t >> 6, lane = t & 63, quad = lane >> 4, l16 = lane & 15;

    floatx4 acc[2][3];
    #pragma unroll
    for (int i = 0; i < 2; ++i)
        #pragma unroll
        for (int jn = 0; jn < 3; ++jn) acc[i][jn] = (floatx4){0.f, 0.f, 0.f, 0.f};

    // prefetch tap 0 W slab into registers
    short8 wreg[8];
    {
        const short8* src = (const short8*)(Wt + (0 * 4 + cog) * 16384);
        #pragma unroll
        for (int i = 0; i < 8; ++i) wreg[i] = src[i * 256 + t];
    }

    for (int tap = 0; tap < 9; ++tap) {
        __syncthreads();   // prev-tap Ws readers done (also covers X staging at tap 0)
        {
            short8* dst = (short8*)Ws;
            #pragma unroll
            for (int i = 0; i < 8; ++i) dst[i * 256 + t] = wreg[i];
        }
        if (tap < 8) {   // prefetch next tap; completes during this tap's MFMAs
            const short8* src = (const short8*)(Wt + ((tap + 1) * 4 + cog) * 16384);
            #pragma unroll
            for (int i = 0; i < 8; ++i) wreg[i] = src[i * 256 + t];
        }
        __syncthreads();

        const int dy = tap / 3, dx = tap % 3;
        int colw[3];
        #pragma unroll
        for (int nt = 0; nt < 3; ++nt) {
            int c = nt * 16 + l16 + dx - 1;
            c = (c < 0) ? c + 48 : (c >= 48 ? c - 48 : c);
            colw[nt] = c;
        }

        #pragma unroll
        for (int kk = 0; kk < 4; ++kk) {
            int chA = kk * 4 + quad;
            short8 a0 = *(const short8*)&Ws[(chA * 128 + wave * 32 + l16) * 8];
            short8 a1 = *(const short8*)&Ws[(chA * 128 + wave * 32 + 16 + l16) * 8];
            #pragma unroll
            for (int nt = 0; nt < 3; ++nt) {
                short8 bf = *(const short8*)&Xs[((chA * 3 + dy) * 48 + colw[nt]) * 8];
                acc[0][nt] = __builtin_amdgcn_mfma_f32_16x16x32_bf16(a0, bf, acc[0][nt], 0, 0, 0);
                acc[1][nt] = __builtin_amdgcn_mfma_f32_16x16x32_bf16(a1, bf, acc[1][nt], 0, 0, 0);
            }
        }
    }

    // Epilogue: C/D layout col=l16 (spatial), row=quad*4+r (co)
    if (cog == 0) {
        #pragma unroll
        for (int mt = 0; mt < 2; ++mt)
            #pragma unroll
            for (int nt = 0; nt < 3; ++nt)
                #pragma unroll
                for (int r = 0; r < 4; ++r) {
                    int n    = y * 48 + nt * 16 + l16;
                    int co_l = wave * 32 + mt * 16 + quad * 4 + r;
                    dout[(b * 256 + co_l) * 2304 + n] = acc[mt][nt][r];
                }
    } else if (cog == 3) {
        #pragma unroll
        for (int mt = 0; mt < 2; ++mt)
            #pragma unroll
            for (int nt = 0; nt < 3; ++nt)
                #pragma unroll
                for (int r = 0; r < 4; ++r) {
                    int n    = y * 48 + nt * 16 + l16;
                    int co_l = wave * 32 + mt * 16 + quad * 4 + r;
                    vbuf[(b * 128 + co_l) * 2304 + n] = (_Float16)acc[mt][nt][r];
                }
    } else {
        _Float16* dst = (cog == 1) ? qT : kT;
        const float scale = (cog == 1) ? 0.360673762f : 1.0f;   // 0.25*log2(e) for q
        #pragma unroll
        for (int mt = 0; mt < 2; ++mt) {
            int hh = wave * 2 + mt;           // head index (co_l>>4)
            #pragma unroll
            for (int nt = 0; nt < 3; ++nt) {
                int n = y * 48 + nt * 16 + l16;
                half4 o;
                #pragma unroll
                for (int r = 0; r < 4; ++r) o[r] = (_Float16)(acc[mt][nt][r] * scale);
                *(half4*)&dst[((b * 8 + hh) * 2304 + n) * 16 + quad * 4] = o;
            }
        }
    }
}

// ---------------------------------------------------------------------------
// Kernel 3: flash-style attention, ZERO LDS staging / zero loop barriers.
// qT/kT are pre-transposed [bh][n][d] by the conv; V is [b][c][n] d-major.
// 16x16x16 layout identity: C/D row (quad*4+r) == A/B k (quad*4+j), so
// exp2(S^T C-frag) IS the P^T B-operand of O^T = mfma(V^T, P^T).
// Row sums via ones-A MFMA: D[r][n] = sum_k P^T[k][n] (full K internal
// reduction -> no shuffles). Block = n-tile 32, 4 waves = (n-half, m-half);
// dual acc chains; 1-deep prefetch of kf/vf. Grid 2304 blocks.
// attnbuf (bf16) layout (b, h, n, d) flat == raw reshape to (b,128,2304).
// ---------------------------------------------------------------------------
__global__ __launch_bounds__(256) void attn_kernel(
    const _Float16* __restrict__ qT, const _Float16* __restrict__ kT,
    const _Float16* __restrict__ vbuf, short* __restrict__ attnbuf)
{
    const int bh = blockIdx.y;
    const int b = bh >> 3, h = bh & 7;
    const int n0 = blockIdx.x * 32;

    __shared__ float Red[2][64][5];

    const int t = threadIdx.x;
    const int wave = t >> 6, lane = t & 63, quad = lane >> 4, l16 = lane & 15;
    const int nh = wave >> 1, mh = wave & 1;

    const _Float16* qTb = qT + (size_t)bh * 2304 * 16;
    const _Float16* kTb = kT + (size_t)bh * 2304 * 16;
    const _Float16* vb  = vbuf + (b * 128 + h * 16) * 2304;

    const int n = n0 + nh * 16 + l16;
    // Q fragment: B[k=d=quad*4+j][n=l16]  (loop-invariant)
    half4 qf = *(const half4*)(qTb + n * 16 + quad * 4);

    const half4 ones = {(_Float16)1.f, (_Float16)1.f, (_Float16)1.f, (_Float16)1.f};

    floatx4 accE = {0.f,0.f,0.f,0.f}, accD = {0.f,0.f,0.f,0.f};
    floatx4 sE   = {0.f,0.f,0.f,0.f}, sD   = {0.f,0.f,0.f,0.f};

    // wave's m-subtiles: m = (2s+mh)*16, s=0..71
    int m0 = mh * 16;
    half4 kf = *(const half4*)(kTb + (m0 + l16) * 16 + quad * 4);
    half4 vf = *(const half4*)(vb + l16 * 2304 + m0 + quad * 4);

    #pragma unroll 8
    for (int s = 0; s < 72; ++s) {
        half4 kc = kf, vc = vf;
        if (s < 71) {
            int m1 = (2 * (s + 1) + mh) * 16;
            kf = *(const half4*)(kTb + (m1 + l16) * 16 + quad * 4);
            vf = *(const half4*)(vb + l16 * 2304 + m1 + quad * 4);
        }
        floatx4 z = {0.f,0.f,0.f,0.f};
        // S^T tile: D[m=quad*4+r][n=l16]
        floatx4 st = __builtin_amdgcn_mfma_f32_16x16x16f16(kc, qf, z, 0, 0, 0);
        // exp2 (scale pre-folded in conv) -> P^T fragment: B[k=m][n=l16]
        half4 pf;
        pf[0] = (_Float16)fast_exp2(st[0]);
        pf[1] = (_Float16)fast_exp2(st[1]);
        pf[2] = (_Float16)fast_exp2(st[2]);
        pf[3] = (_Float16)fast_exp2(st[3]);
        // O^T accum D[d=quad*4+r][n=l16]; row-sums on the MFMA pipe; dual chains
        if (s & 1) {
            accD = __builtin_amdgcn_mfma_f32_16x16x16f16(vc, pf, accD, 0, 0, 0);
            sD   = __builtin_amdgcn_mfma_f32_16x16x16f16(ones, pf, sD, 0, 0, 0);
        } else {
            accE = __builtin_amdgcn_mfma_f32_16x16x16f16(vc, pf, accE, 0, 0, 0);
            sE   = __builtin_amdgcn_mfma_f32_16x16x16f16(ones, pf, sE, 0, 0, 0);
        }
    }

    floatx4 accO;
    #pragma unroll
    for (int r = 0; r < 4; ++r) accO[r] = accE[r] + accD[r];
    float lsum = sE[0] + sD[0];   // full row sum over this wave's m-half

    if (mh == 1) {
        #pragma unroll
        for (int r = 0; r < 4; ++r) Red[nh][lane][r] = accO[r];
        Red[nh][lane][4] = lsum;
    }
    __syncthreads();
    if (mh == 0) {
        #pragma unroll
        for (int r = 0; r < 4; ++r) accO[r] += Red[nh][lane][r];
        lsum += Red[nh][lane][4];
        float rinv = 1.0f / lsum;
        shortx4 o;
        #pragma unroll
        for (int r = 0; r < 4; ++r) o[r] = bf16_short(accO[r] * rinv);
        *(shortx4*)&attnbuf[((size_t)bh * 2304 + n) * 16 + quad * 4] = o;
    }
}

// ---------------------------------------------------------------------------
// Kernel 4: 1x1 conv on raw-reshaped attention buffer. M=128, N=32, K=128.
// Writes d_out (fp32) channels 128..255.
// ---------------------------------------------------------------------------
__global__ __launch_bounds__(256) void conv1x1(
    const short* __restrict__ attnbuf, const short* __restrict__ Wot,
    float* __restrict__ dout)
{
    const int b    = blockIdx.y;
    const int col0 = blockIdx.x * 32;
    constexpr int RSA = 136;              // row stride (shorts), 16B-aligned

    __shared__ short Wo[16 * 128 * 8];
    __shared__ short As[32 * RSA];        // [col][ci]

    const int t = threadIdx.x;
    {   // Wo: contiguous copy
        short8* dst = (short8*)Wo;
        const short8* src = (const short8*)Wot;
        #pragma unroll
        for (int it = 0; it < 8; ++it) dst[it * 256 + t] = src[it * 256 + t];
    }
    {   // As: transpose 128ci x 32col -> [col][ci]
        const short* ab = attnbuf + b * 128 * 2304;
        #pragma unroll
        for (int it = 0; it < 8; ++it) {
            int e = it * 256 + t;
            int ci = e >> 4, cp = e & 15;
            unsigned v = *(const unsigned*)(ab + ci * 2304 + col0 + cp * 2);
            As[(cp * 2) * RSA + ci]     = (short)(v & 0xffff);
            As[(cp * 2 + 1) * RSA + ci] = (short)(v >> 16);
        }
    }
    __syncthreads();

    const int wave = t >> 6, lane = t & 63, quad = lane >> 4, l16 = lane & 15;
    floatx4 acc[2][2];
    #pragma unroll
    for (int i = 0; i < 2; ++i)
        #pragma unroll
        for (int j = 0; j < 2; ++j) acc[i][j] = (floatx4){0.f, 0.f, 0.f, 0.f};

    #pragma unroll
    for (int kk = 0; kk < 4; ++kk) {
        int chA = kk * 4 + quad;
        short8 a0 = *(const short8*)&Wo[(chA * 128 + wave * 32 + l16) * 8];
        short8 a1 = *(const short8*)&Wo[(chA * 128 + wave * 32 + 16 + l16) * 8];
        #pragma unroll
        for (int nt = 0; nt < 2; ++nt) {
            short8 bf = *(const short8*)&As[(nt * 16 + l16) * RSA + kk * 32 + quad * 8];
            acc[0][nt] = __builtin_amdgcn_mfma_f32_16x16x32_bf16(a0, bf, acc[0][nt], 0, 0, 0);
            acc[1][nt] = __builtin_amdgcn_mfma_f32_16x16x32_bf16(a1, bf, acc[1][nt], 0, 0, 0);
        }
    }

    #pragma unroll
    for (int mt = 0; mt < 2; ++mt)
        #pragma unroll
        for (int nt = 0; nt < 2; ++nt)
            #pragma unroll
            for (int r = 0; r < 4; ++r) {
                int co  = wave * 32 + mt * 16 + quad * 4 + r;
                int col = col0 + nt * 16 + l16;
                dout[(b * 256 + 128 + co) * 2304 + col] = acc[mt][nt][r];  // fp32 out
            }
}

// ---------------------------------------------------------------------------
extern "C" void kernel_launch(void* const* d_in, const int* in_sizes, int n_in,
                              void* d_out, int out_size, void* d_ws, size_t ws_size,
                              hipStream_t stream)
{
    const float* x  = (const float*)d_in[0];
    const float* wi = (const float*)d_in[1];
    const float* wq = (const float*)d_in[2];
    const float* wo = (const float*)d_in[3];
    float* dout = (float*)d_out;

    char* ws = (char*)d_ws;
    _Float16* qT   = (_Float16*)(ws);                   // 2,359,296 B
    _Float16* kT   = (_Float16*)(ws + 2359296);         // 2,359,296 B
    _Float16* vbuf = (_Float16*)(ws + 4718592);         // 2,359,296 B
    short* attnbuf = (short*)(ws + 7077888);            // 2,359,296 B (bf16)
    short* Wt      = (short*)(ws + 9437184);            // 1,179,648 B
    short* Wot     = (short*)(ws + 10616832);           // 32,768 B

    transform_w<<<2368, 256, 0, stream>>>(wi, wq, wo, Wt, Wot);
    conv_main<<<dim3(48, 4, 4), 256, 0, stream>>>(x, Wt, dout, qT, kT, vbuf);
    attn_kernel<<<dim3(72, 32), 256, 0, stream>>>(qT, kT, vbuf, attnbuf);
    conv1x1<<<dim3(72, 4), 256, 0, stream>>>(attnbuf, Wot, dout);
}

// Round 9
// 132.413 us; speedup vs baseline: 1.4919x; 1.4919x over previous
//
#include <hip/hip_runtime.h>

typedef __attribute__((ext_vector_type(8))) short short8;
typedef __attribute__((ext_vector_type(4))) short shortx4;
typedef __attribute__((ext_vector_type(4))) float floatx4;
typedef __attribute__((ext_vector_type(4))) _Float16 half4;

__device__ __forceinline__ short bf16_short(float f) {
    unsigned u = __builtin_bit_cast(unsigned, f);
    u = (u + 0x7fff + ((u >> 16) & 1)) >> 16;   // RNE, finite values only
    return (short)u;
}

__device__ __forceinline__ float fast_exp2(float x) {
#if __has_builtin(__builtin_amdgcn_exp2f)
    return __builtin_amdgcn_exp2f(x);
#else
    return __expf(x * 0.6931471805599453f);
#endif
}

// ---------------------------------------------------------------------------
// Kernel 1: relayout weights (fp32 -> bf16) for MFMA A-fragments.
// Wt layout: [tap(9)][cog(4)][chunk(16)][co(128)][j(8)]  (ci = chunk*8+j)
// Wot layout: [chunk(16)][co(128)][j(8)]
// ---------------------------------------------------------------------------
__global__ __launch_bounds__(256) void transform_w(
    const float* __restrict__ wi, const float* __restrict__ wq,
    const float* __restrict__ wo, short* __restrict__ Wt, short* __restrict__ Wot)
{
    int idx = blockIdx.x * 256 + threadIdx.x;
    if (idx < 589824) {
        int j  = idx & 7;
        int t1 = idx >> 3;
        int co = t1 & 127;
        int t2 = t1 >> 7;
        int chunk = t2 & 15;
        int t3 = t2 >> 4;
        int cog = t3 & 3;
        int tap = t3 >> 2;
        int ci = chunk * 8 + j;
        float v;
        if (cog == 0) v = wi[(co * 128 + ci) * 9 + tap];
        else          v = wq[((((cog - 1) * 128) + co) * 128 + ci) * 9 + tap];
        Wt[idx] = bf16_short(v);
    } else if (idx < 589824 + 16384) {
        int i2 = idx - 589824;
        int j  = i2 & 7;
        int co = (i2 >> 3) & 127;
        int chunk = i2 >> 10;
        int ci = chunk * 8 + j;
        Wot[i2] = bf16_short(wo[co * 128 + ci]);
    }
}

// ---------------------------------------------------------------------------
// Kernel 2: fused circular 3x3 convs (init 128ch + qkv 384ch) as implicit GEMM.
// Block = (y-row, cog, b). M=128 (co group), N=48 (cols of row y), K=1152.
// cog==0 -> d_out (fp32) ch 0..127
// cog==1 -> qT  f16 [bh][n][d] transposed (scaled 0.25*log2(e)), half4 stores
// cog==2 -> kT  f16 [bh][n][d] transposed, half4 stores
// cog==3 -> vbuf f16 [b][c][n] (d-major rows, as attn's V A-operand wants)
// The transposed writes exploit: C-regs r=0..3 are d=quad*4+r (contiguous).
// ---------------------------------------------------------------------------
__global__ __launch_bounds__(256) void conv_main(
    const float* __restrict__ x, const short* __restrict__ Wt,
    float* __restrict__ dout, _Float16* __restrict__ qT,
    _Float16* __restrict__ kT, _Float16* __restrict__ vbuf)
{
    const int y   = blockIdx.x;   // 0..47
    const int cog = blockIdx.y;   // 0..3
    const int b   = blockIdx.z;   // 0..3

    __shared__ short Xs[16 * 3 * 48 * 8];   // [(chunk*3+row)*48+col]*8+j
    __shared__ short Ws[16 * 128 * 8];      // [chunk][co][j]

    const int t = threadIdx.x;

    // Stage X rows y-1,y,y+1 (wrapped): 128ci x 3row x 48col, fp32 -> bf16
    {
        const float* xb = x + b * 128 * 2304;
        #pragma unroll 4
        for (int it = 0; it < 36; ++it) {
            int e   = it * 256 + t;          // 0..9215 column pairs
            int ci  = e / 72;
            int r   = e - ci * 72;
            int row = r / 24;
            int cp  = r - row * 24;
            int rowg = y + row - 1;
            rowg = (rowg < 0) ? rowg + 48 : (rowg >= 48 ? rowg - 48 : rowg);
            float2 v = *(const float2*)(xb + (ci * 48 + rowg) * 48 + cp * 2);
            int slot = ((ci >> 3) * 3 + row) * 48 + cp * 2;
            int j = ci & 7;
            Xs[slot * 8 + j]       = bf16_short(v.x);
            Xs[(slot + 1) * 8 + j] = bf16_short(v.y);
        }
    }

    const int wave = t >> 6, lane = t & 63, quad = lane >> 4, l16 = lane & 15;

    floatx4 acc[2][3];
    #pragma unroll
    for (int i = 0; i < 2; ++i)
        #pragma unroll
        for (int jn = 0; jn < 3; ++jn) acc[i][jn] = (floatx4){0.f, 0.f, 0.f, 0.f};

    // prefetch tap 0 W slab into registers
    short8 wreg[8];
    {
        const short8* src = (const short8*)(Wt + (0 * 4 + cog) * 16384);
        #pragma unroll
        for (int i = 0; i < 8; ++i) wreg[i] = src[i * 256 + t];
    }

    for (int tap = 0; tap < 9; ++tap) {
        __syncthreads();   // prev-tap Ws readers done (also covers X staging at tap 0)
        {
            short8* dst = (short8*)Ws;
            #pragma unroll
            for (int i = 0; i < 8; ++i) dst[i * 256 + t] = wreg[i];
        }
        if (tap < 8) {   // prefetch next tap; completes during this tap's MFMAs
            const short8* src = (const short8*)(Wt + ((tap + 1) * 4 + cog) * 16384);
            #pragma unroll
            for (int i = 0; i < 8; ++i) wreg[i] = src[i * 256 + t];
        }
        __syncthreads();

        const int dy = tap / 3, dx = tap % 3;
        int colw[3];
        #pragma unroll
        for (int nt = 0; nt < 3; ++nt) {
            int c = nt * 16 + l16 + dx - 1;
            c = (c < 0) ? c + 48 : (c >= 48 ? c - 48 : c);
            colw[nt] = c;
        }

        #pragma unroll
        for (int kk = 0; kk < 4; ++kk) {
            int chA = kk * 4 + quad;
            short8 a0 = *(const short8*)&Ws[(chA * 128 + wave * 32 + l16) * 8];
            short8 a1 = *(const short8*)&Ws[(chA * 128 + wave * 32 + 16 + l16) * 8];
            #pragma unroll
            for (int nt = 0; nt < 3; ++nt) {
                short8 bf = *(const short8*)&Xs[((chA * 3 + dy) * 48 + colw[nt]) * 8];
                acc[0][nt] = __builtin_amdgcn_mfma_f32_16x16x32_bf16(a0, bf, acc[0][nt], 0, 0, 0);
                acc[1][nt] = __builtin_amdgcn_mfma_f32_16x16x32_bf16(a1, bf, acc[1][nt], 0, 0, 0);
            }
        }
    }

    // Epilogue: C/D layout col=l16 (spatial), row=quad*4+r (co)
    if (cog == 0) {
        #pragma unroll
        for (int mt = 0; mt < 2; ++mt)
            #pragma unroll
            for (int nt = 0; nt < 3; ++nt)
                #pragma unroll
                for (int r = 0; r < 4; ++r) {
                    int n    = y * 48 + nt * 16 + l16;
                    int co_l = wave * 32 + mt * 16 + quad * 4 + r;
                    dout[(b * 256 + co_l) * 2304 + n] = acc[mt][nt][r];
                }
    } else if (cog == 3) {
        #pragma unroll
        for (int mt = 0; mt < 2; ++mt)
            #pragma unroll
            for (int nt = 0; nt < 3; ++nt)
                #pragma unroll
                for (int r = 0; r < 4; ++r) {
                    int n    = y * 48 + nt * 16 + l16;
                    int co_l = wave * 32 + mt * 16 + quad * 4 + r;
                    vbuf[(b * 128 + co_l) * 2304 + n] = (_Float16)acc[mt][nt][r];
                }
    } else {
        _Float16* dst = (cog == 1) ? qT : kT;
        const float scale = (cog == 1) ? 0.360673762f : 1.0f;   // 0.25*log2(e) for q
        #pragma unroll
        for (int mt = 0; mt < 2; ++mt) {
            int hh = wave * 2 + mt;           // head index (co_l>>4)
            #pragma unroll
            for (int nt = 0; nt < 3; ++nt) {
                int n = y * 48 + nt * 16 + l16;
                half4 o;
                #pragma unroll
                for (int r = 0; r < 4; ++r) o[r] = (_Float16)(acc[mt][nt][r] * scale);
                *(half4*)&dst[((b * 8 + hh) * 2304 + n) * 16 + quad * 4] = o;
            }
        }
    }
}

// ---------------------------------------------------------------------------
// Kernel 3: flash attention, register-only P, 4x Q-reuse per K/V load.
// qT/kT pre-transposed [bh][n][d]; V [b][c][n] d-major.
// 16x16x16 identity: C/D row (quad*4+r) == A/B k (quad*4+j), so exp2(S^T
// C-frag) IS the P^T B-operand of O^T = mfma(V^T, P^T).
// Wave owns a 64-row Q-tile (4 loop-invariant q-frags) x one m-quarter
// (576 rows = 36 subtiles): per iter 2 loads feed 8 MFMAs (4 S + 4 PV)
// -> ~3x more issue work per load than R8; 1-deep prefetch.
// Row sums: f32 adds per frag (partial per quad), 2 shuffles at end.
// 4-way cross-wave (m-quarter) combine via LDS; wave w finalizes frag w.
// attnbuf (bf16) layout (b, h, n, d) flat == raw reshape to (b,128,2304).
// ---------------------------------------------------------------------------
__global__ __launch_bounds__(256) void attn_kernel(
    const _Float16* __restrict__ qT, const _Float16* __restrict__ kT,
    const _Float16* __restrict__ vbuf, short* __restrict__ attnbuf)
{
    const int bh = blockIdx.y;
    const int b = bh >> 3, h = bh & 7;
    const int n0 = blockIdx.x * 64;

    __shared__ float Red[4][4][64][5];   // [wave][frag][lane][accO x4, lsum]

    const int t = threadIdx.x;
    const int wave = t >> 6, lane = t & 63, quad = lane >> 4, l16 = lane & 15;

    const _Float16* qTb = qT + (size_t)bh * 2304 * 16;
    const _Float16* kTb = kT + (size_t)bh * 2304 * 16;
    const _Float16* vb  = vbuf + (b * 128 + h * 16) * 2304;

    // 4 loop-invariant Q fragments: B[k=d=quad*4+j][n=l16], n-subtiles f*16
    half4 qf[4];
    #pragma unroll
    for (int f = 0; f < 4; ++f)
        qf[f] = *(const half4*)(qTb + (n0 + f * 16 + l16) * 16 + quad * 4);

    floatx4 accO[4];
    float lsum[4];
    #pragma unroll
    for (int f = 0; f < 4; ++f) { accO[f] = (floatx4){0.f,0.f,0.f,0.f}; lsum[f] = 0.f; }

    const int mbase = wave * 576;   // this wave's m-quarter
    half4 kf = *(const half4*)(kTb + (mbase + l16) * 16 + quad * 4);
    half4 vf = *(const half4*)(vb + l16 * 2304 + mbase + quad * 4);

    #pragma unroll 2
    for (int s = 0; s < 36; ++s) {
        half4 kc = kf, vc = vf;
        if (s < 35) {
            int m1 = mbase + (s + 1) * 16;
            kf = *(const half4*)(kTb + (m1 + l16) * 16 + quad * 4);
            vf = *(const half4*)(vb + l16 * 2304 + m1 + quad * 4);
        }
        floatx4 z = {0.f,0.f,0.f,0.f};
        floatx4 st[4];
        #pragma unroll
        for (int f = 0; f < 4; ++f)   // 4 independent S^T MFMAs share kc
            st[f] = __builtin_amdgcn_mfma_f32_16x16x16f16(kc, qf[f], z, 0, 0, 0);
        #pragma unroll
        for (int f = 0; f < 4; ++f) {
            float p0 = fast_exp2(st[f][0]);
            float p1 = fast_exp2(st[f][1]);
            float p2 = fast_exp2(st[f][2]);
            float p3 = fast_exp2(st[f][3]);
            lsum[f] += (p0 + p1) + (p2 + p3);
            half4 pf;
            pf[0] = (_Float16)p0; pf[1] = (_Float16)p1;
            pf[2] = (_Float16)p2; pf[3] = (_Float16)p3;
            accO[f] = __builtin_amdgcn_mfma_f32_16x16x16f16(vc, pf, accO[f], 0, 0, 0);
        }
    }

    // full row sums over this wave's m-quarter (combine the 4 quads' m-slices)
    #pragma unroll
    for (int f = 0; f < 4; ++f) {
        lsum[f] += __shfl_xor(lsum[f], 16, 64);
        lsum[f] += __shfl_xor(lsum[f], 32, 64);
    }

    #pragma unroll
    for (int f = 0; f < 4; ++f) {
        #pragma unroll
        for (int r = 0; r < 4; ++r) Red[wave][f][lane][r] = accO[f][r];
        Red[wave][f][lane][4] = lsum[f];
    }
    __syncthreads();

    // wave w finalizes frag f=w: sum the 4 m-quarters, normalize, store
    {
        const int f = wave;
        float tot[4] = {0.f, 0.f, 0.f, 0.f};
        float ls = 0.f;
        #pragma unroll
        for (int w = 0; w < 4; ++w) {
            #pragma unroll
            for (int r = 0; r < 4; ++r) tot[r] += Red[w][f][lane][r];
            ls += Red[w][f][lane][4];
        }
        float rinv = 1.0f / ls;
        shortx4 o;
        #pragma unroll
        for (int r = 0; r < 4; ++r) o[r] = bf16_short(tot[r] * rinv);
        int n = n0 + f * 16 + l16;
        *(shortx4*)&attnbuf[((size_t)bh * 2304 + n) * 16 + quad * 4] = o;
    }
}

// ---------------------------------------------------------------------------
// Kernel 4: 1x1 conv on raw-reshaped attention buffer. M=128, N=32, K=128.
// Writes d_out (fp32) channels 128..255.
// ---------------------------------------------------------------------------
__global__ __launch_bounds__(256) void conv1x1(
    const short* __restrict__ attnbuf, const short* __restrict__ Wot,
    float* __restrict__ dout)
{
    const int b    = blockIdx.y;
    const int col0 = blockIdx.x * 32;
    constexpr int RSA = 136;              // row stride (shorts), 16B-aligned

    __shared__ short Wo[16 * 128 * 8];
    __shared__ short As[32 * RSA];        // [col][ci]

    const int t = threadIdx.x;
    {   // Wo: contiguous copy
        short8* dst = (short8*)Wo;
        const short8* src = (const short8*)Wot;
        #pragma unroll
        for (int it = 0; it < 8; ++it) dst[it * 256 + t] = src[it * 256 + t];
    }
    {   // As: transpose 128ci x 32col -> [col][ci]
        const short* ab = attnbuf + b * 128 * 2304;
        #pragma unroll
        for (int it = 0; it < 8; ++it) {
            int e = it * 256 + t;
            int ci = e >> 4, cp = e & 15;
            unsigned v = *(const unsigned*)(ab + ci * 2304 + col0 + cp * 2);
            As[(cp * 2) * RSA + ci]     = (short)(v & 0xffff);
            As[(cp * 2 + 1) * RSA + ci] = (short)(v >> 16);
        }
    }
    __syncthreads();

    const int wave = t >> 6, lane = t & 63, quad = lane >> 4, l16 = lane & 15;
    floatx4 acc[2][2];
    #pragma unroll
    for (int i = 0; i < 2; ++i)
        #pragma unroll
        for (int j = 0; j < 2; ++j) acc[i][j] = (floatx4){0.f, 0.f, 0.f, 0.f};

    #pragma unroll
    for (int kk = 0; kk < 4; ++kk) {
        int chA = kk * 4 + quad;
        short8 a0 = *(const short8*)&Wo[(chA * 128 + wave * 32 + l16) * 8];
        short8 a1 = *(const short8*)&Wo[(chA * 128 + wave * 32 + 16 + l16) * 8];
        #pragma unroll
        for (int nt = 0; nt < 2; ++nt) {
            short8 bf = *(const short8*)&As[(nt * 16 + l16) * RSA + kk * 32 + quad * 8];
            acc[0][nt] = __builtin_amdgcn_mfma_f32_16x16x32_bf16(a0, bf, acc[0][nt], 0, 0, 0);
            acc[1][nt] = __builtin_amdgcn_mfma_f32_16x16x32_bf16(a1, bf, acc[1][nt], 0, 0, 0);
        }
    }

    #pragma unroll
    for (int mt = 0; mt < 2; ++mt)
        #pragma unroll
        for (int nt = 0; nt < 2; ++nt)
            #pragma unroll
            for (int r = 0; r < 4; ++r) {
                int co  = wave * 32 + mt * 16 + quad * 4 + r;
                int col = col0 + nt * 16 + l16;
                dout[(b * 256 + 128 + co) * 2304 + col] = acc[mt][nt][r];  // fp32 out
            }
}

// ---------------------------------------------------------------------------
extern "C" void kernel_launch(void* const* d_in, const int* in_sizes, int n_in,
                              void* d_out, int out_size, void* d_ws, size_t ws_size,
                              hipStream_t stream)
{
    const float* x  = (const float*)d_in[0];
    const float* wi = (const float*)d_in[1];
    const float* wq = (const float*)d_in[2];
    const float* wo = (const float*)d_in[3];
    float* dout = (float*)d_out;

    char* ws = (char*)d_ws;
    _Float16* qT   = (_Float16*)(ws);                   // 2,359,296 B
    _Float16* kT   = (_Float16*)(ws + 2359296);         // 2,359,296 B
    _Float16* vbuf = (_Float16*)(ws + 4718592);         // 2,359,296 B
    short* attnbuf = (short*)(ws + 7077888);            // 2,359,296 B (bf16)
    short* Wt      = (short*)(ws + 9437184);            // 1,179,648 B
    short* Wot     = (short*)(ws + 10616832);           // 32,768 B

    transform_w<<<2368, 256, 0, stream>>>(wi, wq, wo, Wt, Wot);
    conv_main<<<dim3(48, 4, 4), 256, 0, stream>>>(x, Wt, dout, qT, kT, vbuf);
    attn_kernel<<<dim3(36, 32), 256, 0, stream>>>(qT, kT, vbuf, attnbuf);
    conv1x1<<<dim3(72, 4), 256, 0, stream>>>(attnbuf, Wot, dout);
}

// Round 10
// 124.031 us; speedup vs baseline: 1.5928x; 1.0676x over previous
//
#include <hip/hip_runtime.h>

typedef __attribute__((ext_vector_type(8))) short short8;
typedef __attribute__((ext_vector_type(4))) short shortx4;
typedef __attribute__((ext_vector_type(4))) float floatx4;
typedef __attribute__((ext_vector_type(4))) _Float16 half4;

__device__ __forceinline__ short bf16_short(float f) {
    unsigned u = __builtin_bit_cast(unsigned, f);
    u = (u + 0x7fff + ((u >> 16) & 1)) >> 16;   // RNE, finite values only
    return (short)u;
}

__device__ __forceinline__ float fast_exp2(float x) {
#if __has_builtin(__builtin_amdgcn_exp2f)
    return __builtin_amdgcn_exp2f(x);
#else
    return __expf(x * 0.6931471805599453f);
#endif
}

// ---------------------------------------------------------------------------
// Kernel 1: relayout weights (fp32 -> bf16) for MFMA A-fragments.
// Wt layout: [tap(9)][cog(4)][chunk(16)][co(128)][j(8)]  (ci = chunk*8+j)
// Wot layout: [chunk(16)][co(128)][j(8)]
// ---------------------------------------------------------------------------
__global__ __launch_bounds__(256) void transform_w(
    const float* __restrict__ wi, const float* __restrict__ wq,
    const float* __restrict__ wo, short* __restrict__ Wt, short* __restrict__ Wot)
{
    int idx = blockIdx.x * 256 + threadIdx.x;
    if (idx < 589824) {
        int j  = idx & 7;
        int t1 = idx >> 3;
        int co = t1 & 127;
        int t2 = t1 >> 7;
        int chunk = t2 & 15;
        int t3 = t2 >> 4;
        int cog = t3 & 3;
        int tap = t3 >> 2;
        int ci = chunk * 8 + j;
        float v;
        if (cog == 0) v = wi[(co * 128 + ci) * 9 + tap];
        else          v = wq[((((cog - 1) * 128) + co) * 128 + ci) * 9 + tap];
        Wt[idx] = bf16_short(v);
    } else if (idx < 589824 + 16384) {
        int i2 = idx - 589824;
        int j  = i2 & 7;
        int co = (i2 >> 3) & 127;
        int chunk = i2 >> 10;
        int ci = chunk * 8 + j;
        Wot[i2] = bf16_short(wo[co * 128 + ci]);
    }
}

// ---------------------------------------------------------------------------
// Kernel 2: fused circular 3x3 convs (init 128ch + qkv 384ch), implicit GEMM.
// Block = (y-row, cog, b). M=128, N=48, K=1152.
// R10: W LDS staging DELETED. A-frags come straight from global Wt
// (lane-consecutive 16B -> coalesced, L2-resident, each frag feeds 3 MFMAs),
// register double-buffered one tap ahead. ONE barrier total (after X stage).
// cog==0 -> d_out fp32 ch 0..127; cog==1 -> qT (x0.25*log2e); cog==2 -> kT;
// cog==3 -> vbuf. qT/kT written pre-transposed [bh][n][d] via C-reg identity.
// ---------------------------------------------------------------------------
__global__ __launch_bounds__(256) void conv_main(
    const float* __restrict__ x, const short* __restrict__ Wt,
    float* __restrict__ dout, _Float16* __restrict__ qT,
    _Float16* __restrict__ kT, _Float16* __restrict__ vbuf)
{
    const int y   = blockIdx.x;   // 0..47
    const int cog = blockIdx.y;   // 0..3
    const int b   = blockIdx.z;   // 0..3

    __shared__ short Xs[16 * 3 * 48 * 8];   // [(chunk*3+row)*48+col]*8+j

    const int t = threadIdx.x;
    const int wave = t >> 6, lane = t & 63, quad = lane >> 4, l16 = lane & 15;

    // A-frag global base for this (cog, wave, quad, l16)
    const short* wA = Wt + (size_t)cog * 16384 + (wave * 32 + l16) * 8;
    // frag addr: wA + tap*65536 + chA*1024 (+128 for the +16 co half)

    short8 A[2][8];   // [buf][kk*2+half], double-buffered across taps
    #pragma unroll
    for (int kk = 0; kk < 4; ++kk) {
        int chA = kk * 4 + quad;
        A[0][kk * 2 + 0] = *(const short8*)(wA + chA * 1024);
        A[0][kk * 2 + 1] = *(const short8*)(wA + chA * 1024 + 128);
    }

    // Stage X rows y-1,y,y+1 (wrapped): 128ci x 3row x 48col, fp32 -> bf16
    {
        const float* xb = x + b * 128 * 2304;
        #pragma unroll 4
        for (int it = 0; it < 36; ++it) {
            int e   = it * 256 + t;          // 0..9215 column pairs
            int ci  = e / 72;
            int r   = e - ci * 72;
            int row = r / 24;
            int cp  = r - row * 24;
            int rowg = y + row - 1;
            rowg = (rowg < 0) ? rowg + 48 : (rowg >= 48 ? rowg - 48 : rowg);
            float2 v = *(const float2*)(xb + (ci * 48 + rowg) * 48 + cp * 2);
            int slot = ((ci >> 3) * 3 + row) * 48 + cp * 2;
            int j = ci & 7;
            Xs[slot * 8 + j]       = bf16_short(v.x);
            Xs[(slot + 1) * 8 + j] = bf16_short(v.y);
        }
    }

    floatx4 acc[2][3];
    #pragma unroll
    for (int i = 0; i < 2; ++i)
        #pragma unroll
        for (int jn = 0; jn < 3; ++jn) acc[i][jn] = (floatx4){0.f, 0.f, 0.f, 0.f};

    __syncthreads();   // the only barrier: Xs ready

    #pragma unroll
    for (int tap = 0; tap < 9; ++tap) {
        const int cur = tap & 1;
        if (tap < 8) {   // prefetch next tap's A-frags; lands during MFMAs
            const short* wn = wA + (tap + 1) * 65536;
            #pragma unroll
            for (int kk = 0; kk < 4; ++kk) {
                int chA = kk * 4 + quad;
                A[cur ^ 1][kk * 2 + 0] = *(const short8*)(wn + chA * 1024);
                A[cur ^ 1][kk * 2 + 1] = *(const short8*)(wn + chA * 1024 + 128);
            }
        }

        const int dy = tap / 3, dx = tap % 3;
        int colw[3];
        #pragma unroll
        for (int nt = 0; nt < 3; ++nt) {
            int c = nt * 16 + l16 + dx - 1;
            c = (c < 0) ? c + 48 : (c >= 48 ? c - 48 : c);
            colw[nt] = c;
        }

        #pragma unroll
        for (int kk = 0; kk < 4; ++kk) {
            int chA = kk * 4 + quad;
            short8 a0 = A[cur][kk * 2 + 0];
            short8 a1 = A[cur][kk * 2 + 1];
            #pragma unroll
            for (int nt = 0; nt < 3; ++nt) {
                short8 bf = *(const short8*)&Xs[((chA * 3 + dy) * 48 + colw[nt]) * 8];
                acc[0][nt] = __builtin_amdgcn_mfma_f32_16x16x32_bf16(a0, bf, acc[0][nt], 0, 0, 0);
                acc[1][nt] = __builtin_amdgcn_mfma_f32_16x16x32_bf16(a1, bf, acc[1][nt], 0, 0, 0);
            }
        }
    }

    // Epilogue: C/D layout col=l16 (spatial), row=quad*4+r (co)
    if (cog == 0) {
        #pragma unroll
        for (int mt = 0; mt < 2; ++mt)
            #pragma unroll
            for (int nt = 0; nt < 3; ++nt)
                #pragma unroll
                for (int r = 0; r < 4; ++r) {
                    int n    = y * 48 + nt * 16 + l16;
                    int co_l = wave * 32 + mt * 16 + quad * 4 + r;
                    dout[(b * 256 + co_l) * 2304 + n] = acc[mt][nt][r];
                }
    } else if (cog == 3) {
        #pragma unroll
        for (int mt = 0; mt < 2; ++mt)
            #pragma unroll
            for (int nt = 0; nt < 3; ++nt)
                #pragma unroll
                for (int r = 0; r < 4; ++r) {
                    int n    = y * 48 + nt * 16 + l16;
                    int co_l = wave * 32 + mt * 16 + quad * 4 + r;
                    vbuf[(b * 128 + co_l) * 2304 + n] = (_Float16)acc[mt][nt][r];
                }
    } else {
        _Float16* dst = (cog == 1) ? qT : kT;
        const float scale = (cog == 1) ? 0.360673762f : 1.0f;   // 0.25*log2(e) for q
        #pragma unroll
        for (int mt = 0; mt < 2; ++mt) {
            int hh = wave * 2 + mt;           // head index (co_l>>4)
            #pragma unroll
            for (int nt = 0; nt < 3; ++nt) {
                int n = y * 48 + nt * 16 + l16;
                half4 o;
                #pragma unroll
                for (int r = 0; r < 4; ++r) o[r] = (_Float16)(acc[mt][nt][r] * scale);
                *(half4*)&dst[((b * 8 + hh) * 2304 + n) * 16 + quad * 4] = o;
            }
        }
    }
}

// ---------------------------------------------------------------------------
// Kernel 3: flash attention, register-only P, 4x Q-reuse per K/V load.
// (unchanged from R9 — 132 us config; attn ~42 us)
// ---------------------------------------------------------------------------
__global__ __launch_bounds__(256) void attn_kernel(
    const _Float16* __restrict__ qT, const _Float16* __restrict__ kT,
    const _Float16* __restrict__ vbuf, short* __restrict__ attnbuf)
{
    const int bh = blockIdx.y;
    const int b = bh >> 3, h = bh & 7;
    const int n0 = blockIdx.x * 64;

    __shared__ float Red[4][4][64][5];   // [wave][frag][lane][accO x4, lsum]

    const int t = threadIdx.x;
    const int wave = t >> 6, lane = t & 63, quad = lane >> 4, l16 = lane & 15;

    const _Float16* qTb = qT + (size_t)bh * 2304 * 16;
    const _Float16* kTb = kT + (size_t)bh * 2304 * 16;
    const _Float16* vb  = vbuf + (b * 128 + h * 16) * 2304;

    half4 qf[4];
    #pragma unroll
    for (int f = 0; f < 4; ++f)
        qf[f] = *(const half4*)(qTb + (n0 + f * 16 + l16) * 16 + quad * 4);

    floatx4 accO[4];
    float lsum[4];
    #pragma unroll
    for (int f = 0; f < 4; ++f) { accO[f] = (floatx4){0.f,0.f,0.f,0.f}; lsum[f] = 0.f; }

    const int mbase = wave * 576;   // this wave's m-quarter
    half4 kf = *(const half4*)(kTb + (mbase + l16) * 16 + quad * 4);
    half4 vf = *(const half4*)(vb + l16 * 2304 + mbase + quad * 4);

    #pragma unroll 2
    for (int s = 0; s < 36; ++s) {
        half4 kc = kf, vc = vf;
        if (s < 35) {
            int m1 = mbase + (s + 1) * 16;
            kf = *(const half4*)(kTb + (m1 + l16) * 16 + quad * 4);
            vf = *(const half4*)(vb + l16 * 2304 + m1 + quad * 4);
        }
        floatx4 z = {0.f,0.f,0.f,0.f};
        floatx4 st[4];
        #pragma unroll
        for (int f = 0; f < 4; ++f)
            st[f] = __builtin_amdgcn_mfma_f32_16x16x16f16(kc, qf[f], z, 0, 0, 0);
        #pragma unroll
        for (int f = 0; f < 4; ++f) {
            float p0 = fast_exp2(st[f][0]);
            float p1 = fast_exp2(st[f][1]);
            float p2 = fast_exp2(st[f][2]);
            float p3 = fast_exp2(st[f][3]);
            lsum[f] += (p0 + p1) + (p2 + p3);
            half4 pf;
            pf[0] = (_Float16)p0; pf[1] = (_Float16)p1;
            pf[2] = (_Float16)p2; pf[3] = (_Float16)p3;
            accO[f] = __builtin_amdgcn_mfma_f32_16x16x16f16(vc, pf, accO[f], 0, 0, 0);
        }
    }

    #pragma unroll
    for (int f = 0; f < 4; ++f) {
        lsum[f] += __shfl_xor(lsum[f], 16, 64);
        lsum[f] += __shfl_xor(lsum[f], 32, 64);
    }

    #pragma unroll
    for (int f = 0; f < 4; ++f) {
        #pragma unroll
        for (int r = 0; r < 4; ++r) Red[wave][f][lane][r] = accO[f][r];
        Red[wave][f][lane][4] = lsum[f];
    }
    __syncthreads();

    {
        const int f = wave;
        float tot[4] = {0.f, 0.f, 0.f, 0.f};
        float ls = 0.f;
        #pragma unroll
        for (int w = 0; w < 4; ++w) {
            #pragma unroll
            for (int r = 0; r < 4; ++r) tot[r] += Red[w][f][lane][r];
            ls += Red[w][f][lane][4];
        }
        float rinv = 1.0f / ls;
        shortx4 o;
        #pragma unroll
        for (int r = 0; r < 4; ++r) o[r] = bf16_short(tot[r] * rinv);
        int n = n0 + f * 16 + l16;
        *(shortx4*)&attnbuf[((size_t)bh * 2304 + n) * 16 + quad * 4] = o;
    }
}

// ---------------------------------------------------------------------------
// Kernel 4: 1x1 conv on raw-reshaped attention buffer. M=128, N=32, K=128.
// Writes d_out (fp32) channels 128..255.
// ---------------------------------------------------------------------------
__global__ __launch_bounds__(256) void conv1x1(
    const short* __restrict__ attnbuf, const short* __restrict__ Wot,
    float* __restrict__ dout)
{
    const int b    = blockIdx.y;
    const int col0 = blockIdx.x * 32;
    constexpr int RSA = 136;              // row stride (shorts), 16B-aligned

    __shared__ short Wo[16 * 128 * 8];
    __shared__ short As[32 * RSA];        // [col][ci]

    const int t = threadIdx.x;
    {   // Wo: contiguous copy
        short8* dst = (short8*)Wo;
        const short8* src = (const short8*)Wot;
        #pragma unroll
        for (int it = 0; it < 8; ++it) dst[it * 256 + t] = src[it * 256 + t];
    }
    {   // As: transpose 128ci x 32col -> [col][ci]
        const short* ab = attnbuf + b * 128 * 2304;
        #pragma unroll
        for (int it = 0; it < 8; ++it) {
            int e = it * 256 + t;
            int ci = e >> 4, cp = e & 15;
            unsigned v = *(const unsigned*)(ab + ci * 2304 + col0 + cp * 2);
            As[(cp * 2) * RSA + ci]     = (short)(v & 0xffff);
            As[(cp * 2 + 1) * RSA + ci] = (short)(v >> 16);
        }
    }
    __syncthreads();

    const int wave = t >> 6, lane = t & 63, quad = lane >> 4, l16 = lane & 15;
    floatx4 acc[2][2];
    #pragma unroll
    for (int i = 0; i < 2; ++i)
        #pragma unroll
        for (int j = 0; j < 2; ++j) acc[i][j] = (floatx4){0.f, 0.f, 0.f, 0.f};

    #pragma unroll
    for (int kk = 0; kk < 4; ++kk) {
        int chA = kk * 4 + quad;
        short8 a0 = *(const short8*)&Wo[(chA * 128 + wave * 32 + l16) * 8];
        short8 a1 = *(const short8*)&Wo[(chA * 128 + wave * 32 + 16 + l16) * 8];
        #pragma unroll
        for (int nt = 0; nt < 2; ++nt) {
            short8 bf = *(const short8*)&As[(nt * 16 + l16) * RSA + kk * 32 + quad * 8];
            acc[0][nt] = __builtin_amdgcn_mfma_f32_16x16x32_bf16(a0, bf, acc[0][nt], 0, 0, 0);
            acc[1][nt] = __builtin_amdgcn_mfma_f32_16x16x32_bf16(a1, bf, acc[1][nt], 0, 0, 0);
        }
    }

    #pragma unroll
    for (int mt = 0; mt < 2; ++mt)
        #pragma unroll
        for (int nt = 0; nt < 2; ++nt)
            #pragma unroll
            for (int r = 0; r < 4; ++r) {
                int co  = wave * 32 + mt * 16 + quad * 4 + r;
                int col = col0 + nt * 16 + l16;
                dout[(b * 256 + 128 + co) * 2304 + col] = acc[mt][nt][r];  // fp32 out
            }
}

// ---------------------------------------------------------------------------
extern "C" void kernel_launch(void* const* d_in, const int* in_sizes, int n_in,
                              void* d_out, int out_size, void* d_ws, size_t ws_size,
                              hipStream_t stream)
{
    const float* x  = (const float*)d_in[0];
    const float* wi = (const float*)d_in[1];
    const float* wq = (const float*)d_in[2];
    const float* wo = (const float*)d_in[3];
    float* dout = (float*)d_out;

    char* ws = (char*)d_ws;
    _Float16* qT   = (_Float16*)(ws);                   // 2,359,296 B
    _Float16* kT   = (_Float16*)(ws + 2359296);         // 2,359,296 B
    _Float16* vbuf = (_Float16*)(ws + 4718592);         // 2,359,296 B
    short* attnbuf = (short*)(ws + 7077888);            // 2,359,296 B (bf16)
    short* Wt      = (short*)(ws + 9437184);            // 1,179,648 B
    short* Wot     = (short*)(ws + 10616832);           // 32,768 B

    transform_w<<<2368, 256, 0, stream>>>(wi, wq, wo, Wt, Wot);
    conv_main<<<dim3(48, 4, 4), 256, 0, stream>>>(x, Wt, dout, qT, kT, vbuf);
    attn_kernel<<<dim3(36, 32), 256, 0, stream>>>(qT, kT, vbuf, attnbuf);
    conv1x1<<<dim3(72, 4), 256, 0, stream>>>(attnbuf, Wot, dout);
}

// Round 11
// 120.339 us; speedup vs baseline: 1.6416x; 1.0307x over previous
//
#include <hip/hip_runtime.h>

typedef __attribute__((ext_vector_type(8))) short short8;
typedef __attribute__((ext_vector_type(4))) short shortx4;
typedef __attribute__((ext_vector_type(4))) float floatx4;
typedef __attribute__((ext_vector_type(4))) _Float16 half4;

__device__ __forceinline__ short bf16_short(float f) {
    unsigned u = __builtin_bit_cast(unsigned, f);
    u = (u + 0x7fff + ((u >> 16) & 1)) >> 16;   // RNE, finite values only
    return (short)u;
}

__device__ __forceinline__ float fast_exp2(float x) {
#if __has_builtin(__builtin_amdgcn_exp2f)
    return __builtin_amdgcn_exp2f(x);
#else
    return __expf(x * 0.6931471805599453f);
#endif
}

// ---------------------------------------------------------------------------
// Kernel 1: one-time data prep.
// Blocks [0,2368): weights fp32 -> bf16 MFMA A-layout.
//   Wt:  [tap(9)][cog(4)][chunk(16)][co(128)][j(8)]  (ci = chunk*8+j)
//   Wot: [chunk(16)][co(128)][j(8)]
// Blocks [2368,2944): X fp32 -> bf16 fragment layout
//   Xt:  [b(4)][chunk(16)][row(48)][col(48)][j(8)]   (ci = chunk*8+j)
//   -> conv_main staging becomes a pure b128 memcpy.
// ---------------------------------------------------------------------------
__global__ __launch_bounds__(256) void transform_w(
    const float* __restrict__ wi, const float* __restrict__ wq,
    const float* __restrict__ wo, const float* __restrict__ x,
    short* __restrict__ Wt, short* __restrict__ Wot, short* __restrict__ Xt)
{
    if (blockIdx.x < 2368) {
        int idx = blockIdx.x * 256 + threadIdx.x;
        if (idx < 589824) {
            int j  = idx & 7;
            int t1 = idx >> 3;
            int co = t1 & 127;
            int t2 = t1 >> 7;
            int chunk = t2 & 15;
            int t3 = t2 >> 4;
            int cog = t3 & 3;
            int tap = t3 >> 2;
            int ci = chunk * 8 + j;
            float v;
            if (cog == 0) v = wi[(co * 128 + ci) * 9 + tap];
            else          v = wq[((((cog - 1) * 128) + co) * 128 + ci) * 9 + tap];
            Wt[idx] = bf16_short(v);
        } else {
            int i2 = idx - 589824;
            int j  = i2 & 7;
            int co = (i2 >> 3) & 127;
            int chunk = i2 >> 10;
            int ci = chunk * 8 + j;
            Wot[i2] = bf16_short(wo[co * 128 + ci]);
        }
    } else {
        // X transpose+convert: xid over [b][chunk][row][col]
        int xid = (blockIdx.x - 2368) * 256 + threadIdx.x;   // 0..147455
        int col   = xid % 48;
        int row   = (xid / 48) % 48;
        int chunk = (xid / 2304) % 16;
        int b     = xid / 36864;
        const float* xs = x + ((b * 128 + chunk * 8) * 48 + row) * 48 + col;
        short8 o;
        #pragma unroll
        for (int j = 0; j < 8; ++j) o[j] = bf16_short(xs[j * 2304]);
        *(short8*)&Xt[(size_t)xid * 8] = o;
    }
}

// ---------------------------------------------------------------------------
// Kernel 2: fused circular 3x3 convs (init 128ch + qkv 384ch), implicit GEMM.
// Block = (y-row, cog, b). M=128, N=48, K=1152.
// X staging = pure b128 memcpy from pre-transposed Xt (9 copies/thread).
// A-frags straight from global Wt, register double-buffered one tap ahead.
// ONE barrier total. cog==0 -> d_out fp32 ch 0..127; cog==1 -> qT
// (x0.25*log2e); cog==2 -> kT; cog==3 -> vbuf. qT/kT pre-transposed
// [bh][n][d] via the C-reg identity (r=0..3 <-> d=quad*4+r contiguous).
// ---------------------------------------------------------------------------
__global__ __launch_bounds__(256) void conv_main(
    const short* __restrict__ Xt, const short* __restrict__ Wt,
    float* __restrict__ dout, _Float16* __restrict__ qT,
    _Float16* __restrict__ kT, _Float16* __restrict__ vbuf)
{
    const int y   = blockIdx.x;   // 0..47
    const int cog = blockIdx.y;   // 0..3
    const int b   = blockIdx.z;   // 0..3

    __shared__ short Xs[16 * 3 * 48 * 8];   // [(chunk*3+row)*48+col]*8+j

    const int t = threadIdx.x;
    const int wave = t >> 6, lane = t & 63, quad = lane >> 4, l16 = lane & 15;

    // A-frag global base for this (cog, wave, quad, l16)
    const short* wA = Wt + (size_t)cog * 16384 + (wave * 32 + l16) * 8;

    short8 A[2][8];   // [buf][kk*2+half], double-buffered across taps
    #pragma unroll
    for (int kk = 0; kk < 4; ++kk) {
        int chA = kk * 4 + quad;
        A[0][kk * 2 + 0] = *(const short8*)(wA + chA * 1024);
        A[0][kk * 2 + 1] = *(const short8*)(wA + chA * 1024 + 128);
    }

    // Stage X rows y-1,y,y+1 (wrapped): pure b128 copies from Xt
    {
        const short* xtb = Xt + (size_t)b * 16 * 48 * 48 * 8;
        #pragma unroll
        for (int it = 0; it < 9; ++it) {
            int w     = it * 256 + t;        // 0..2303
            int col   = w % 48;
            int row3  = (w / 48) % 3;
            int chunk = w / 144;
            int rowg  = y + row3 - 1;
            rowg = (rowg < 0) ? rowg + 48 : (rowg >= 48 ? rowg - 48 : rowg);
            short8 v = *(const short8*)&xtb[((chunk * 48 + rowg) * 48 + col) * 8];
            *(short8*)&Xs[((chunk * 3 + row3) * 48 + col) * 8] = v;
        }
    }

    floatx4 acc[2][3];
    #pragma unroll
    for (int i = 0; i < 2; ++i)
        #pragma unroll
        for (int jn = 0; jn < 3; ++jn) acc[i][jn] = (floatx4){0.f, 0.f, 0.f, 0.f};

    __syncthreads();   // the only barrier: Xs ready

    #pragma unroll
    for (int tap = 0; tap < 9; ++tap) {
        const int cur = tap & 1;
        if (tap < 8) {   // prefetch next tap's A-frags; lands during MFMAs
            const short* wn = wA + (tap + 1) * 65536;
            #pragma unroll
            for (int kk = 0; kk < 4; ++kk) {
                int chA = kk * 4 + quad;
                A[cur ^ 1][kk * 2 + 0] = *(const short8*)(wn + chA * 1024);
                A[cur ^ 1][kk * 2 + 1] = *(const short8*)(wn + chA * 1024 + 128);
            }
        }

        const int dy = tap / 3, dx = tap % 3;
        int colw[3];
        #pragma unroll
        for (int nt = 0; nt < 3; ++nt) {
            int c = nt * 16 + l16 + dx - 1;
            c = (c < 0) ? c + 48 : (c >= 48 ? c - 48 : c);
            colw[nt] = c;
        }

        #pragma unroll
        for (int kk = 0; kk < 4; ++kk) {
            int chA = kk * 4 + quad;
            short8 a0 = A[cur][kk * 2 + 0];
            short8 a1 = A[cur][kk * 2 + 1];
            #pragma unroll
            for (int nt = 0; nt < 3; ++nt) {
                short8 bf = *(const short8*)&Xs[((chA * 3 + dy) * 48 + colw[nt]) * 8];
                acc[0][nt] = __builtin_amdgcn_mfma_f32_16x16x32_bf16(a0, bf, acc[0][nt], 0, 0, 0);
                acc[1][nt] = __builtin_amdgcn_mfma_f32_16x16x32_bf16(a1, bf, acc[1][nt], 0, 0, 0);
            }
        }
    }

    // Epilogue: C/D layout col=l16 (spatial), row=quad*4+r (co)
    if (cog == 0) {
        #pragma unroll
        for (int mt = 0; mt < 2; ++mt)
            #pragma unroll
            for (int nt = 0; nt < 3; ++nt)
                #pragma unroll
                for (int r = 0; r < 4; ++r) {
                    int n    = y * 48 + nt * 16 + l16;
                    int co_l = wave * 32 + mt * 16 + quad * 4 + r;
                    dout[(b * 256 + co_l) * 2304 + n] = acc[mt][nt][r];
                }
    } else if (cog == 3) {
        #pragma unroll
        for (int mt = 0; mt < 2; ++mt)
            #pragma unroll
            for (int nt = 0; nt < 3; ++nt)
                #pragma unroll
                for (int r = 0; r < 4; ++r) {
                    int n    = y * 48 + nt * 16 + l16;
                    int co_l = wave * 32 + mt * 16 + quad * 4 + r;
                    vbuf[(b * 128 + co_l) * 2304 + n] = (_Float16)acc[mt][nt][r];
                }
    } else {
        _Float16* dst = (cog == 1) ? qT : kT;
        const float scale = (cog == 1) ? 0.360673762f : 1.0f;   // 0.25*log2(e) for q
        #pragma unroll
        for (int mt = 0; mt < 2; ++mt) {
            int hh = wave * 2 + mt;           // head index (co_l>>4)
            #pragma unroll
            for (int nt = 0; nt < 3; ++nt) {
                int n = y * 48 + nt * 16 + l16;
                half4 o;
                #pragma unroll
                for (int r = 0; r < 4; ++r) o[r] = (_Float16)(acc[mt][nt][r] * scale);
                *(half4*)&dst[((b * 8 + hh) * 2304 + n) * 16 + quad * 4] = o;
            }
        }
    }
}

// ---------------------------------------------------------------------------
// Kernel 3: flash attention, register-only P, 4x Q-reuse per K/V load.
// (unchanged from R9)
// ---------------------------------------------------------------------------
__global__ __launch_bounds__(256) void attn_kernel(
    const _Float16* __restrict__ qT, const _Float16* __restrict__ kT,
    const _Float16* __restrict__ vbuf, short* __restrict__ attnbuf)
{
    const int bh = blockIdx.y;
    const int b = bh >> 3, h = bh & 7;
    const int n0 = blockIdx.x * 64;

    __shared__ float Red[4][4][64][5];   // [wave][frag][lane][accO x4, lsum]

    const int t = threadIdx.x;
    const int wave = t >> 6, lane = t & 63, quad = lane >> 4, l16 = lane & 15;

    const _Float16* qTb = qT + (size_t)bh * 2304 * 16;
    const _Float16* kTb = kT + (size_t)bh * 2304 * 16;
    const _Float16* vb  = vbuf + (b * 128 + h * 16) * 2304;

    half4 qf[4];
    #pragma unroll
    for (int f = 0; f < 4; ++f)
        qf[f] = *(const half4*)(qTb + (n0 + f * 16 + l16) * 16 + quad * 4);

    floatx4 accO[4];
    float lsum[4];
    #pragma unroll
    for (int f = 0; f < 4; ++f) { accO[f] = (floatx4){0.f,0.f,0.f,0.f}; lsum[f] = 0.f; }

    const int mbase = wave * 576;   // this wave's m-quarter
    half4 kf = *(const half4*)(kTb + (mbase + l16) * 16 + quad * 4);
    half4 vf = *(const half4*)(vb + l16 * 2304 + mbase + quad * 4);

    #pragma unroll 2
    for (int s = 0; s < 36; ++s) {
        half4 kc = kf, vc = vf;
        if (s < 35) {
            int m1 = mbase + (s + 1) * 16;
            kf = *(const half4*)(kTb + (m1 + l16) * 16 + quad * 4);
            vf = *(const half4*)(vb + l16 * 2304 + m1 + quad * 4);
        }
        floatx4 z = {0.f,0.f,0.f,0.f};
        floatx4 st[4];
        #pragma unroll
        for (int f = 0; f < 4; ++f)
            st[f] = __builtin_amdgcn_mfma_f32_16x16x16f16(kc, qf[f], z, 0, 0, 0);
        #pragma unroll
        for (int f = 0; f < 4; ++f) {
            float p0 = fast_exp2(st[f][0]);
            float p1 = fast_exp2(st[f][1]);
            float p2 = fast_exp2(st[f][2]);
            float p3 = fast_exp2(st[f][3]);
            lsum[f] += (p0 + p1) + (p2 + p3);
            half4 pf;
            pf[0] = (_Float16)p0; pf[1] = (_Float16)p1;
            pf[2] = (_Float16)p2; pf[3] = (_Float16)p3;
            accO[f] = __builtin_amdgcn_mfma_f32_16x16x16f16(vc, pf, accO[f], 0, 0, 0);
        }
    }

    #pragma unroll
    for (int f = 0; f < 4; ++f) {
        lsum[f] += __shfl_xor(lsum[f], 16, 64);
        lsum[f] += __shfl_xor(lsum[f], 32, 64);
    }

    #pragma unroll
    for (int f = 0; f < 4; ++f) {
        #pragma unroll
        for (int r = 0; r < 4; ++r) Red[wave][f][lane][r] = accO[f][r];
        Red[wave][f][lane][4] = lsum[f];
    }
    __syncthreads();

    {
        const int f = wave;
        float tot[4] = {0.f, 0.f, 0.f, 0.f};
        float ls = 0.f;
        #pragma unroll
        for (int w = 0; w < 4; ++w) {
            #pragma unroll
            for (int r = 0; r < 4; ++r) tot[r] += Red[w][f][lane][r];
            ls += Red[w][f][lane][4];
        }
        float rinv = 1.0f / ls;
        shortx4 o;
        #pragma unroll
        for (int r = 0; r < 4; ++r) o[r] = bf16_short(tot[r] * rinv);
        int n = n0 + f * 16 + l16;
        *(shortx4*)&attnbuf[((size_t)bh * 2304 + n) * 16 + quad * 4] = o;
    }
}

// ---------------------------------------------------------------------------
// Kernel 4: 1x1 conv on raw-reshaped attention buffer. M=128, N=32, K=128.
// Writes d_out (fp32) channels 128..255.
// ---------------------------------------------------------------------------
__global__ __launch_bounds__(256) void conv1x1(
    const short* __restrict__ attnbuf, const short* __restrict__ Wot,
    float* __restrict__ dout)
{
    const int b    = blockIdx.y;
    const int col0 = blockIdx.x * 32;
    constexpr int RSA = 136;              // row stride (shorts), 16B-aligned

    __shared__ short Wo[16 * 128 * 8];
    __shared__ short As[32 * RSA];        // [col][ci]

    const int t = threadIdx.x;
    {   // Wo: contiguous copy
        short8* dst = (short8*)Wo;
        const short8* src = (const short8*)Wot;
        #pragma unroll
        for (int it = 0; it < 8; ++it) dst[it * 256 + t] = src[it * 256 + t];
    }
    {   // As: transpose 128ci x 32col -> [col][ci]
        const short* ab = attnbuf + b * 128 * 2304;
        #pragma unroll
        for (int it = 0; it < 8; ++it) {
            int e = it * 256 + t;
            int ci = e >> 4, cp = e & 15;
            unsigned v = *(const unsigned*)(ab + ci * 2304 + col0 + cp * 2);
            As[(cp * 2) * RSA + ci]     = (short)(v & 0xffff);
            As[(cp * 2 + 1) * RSA + ci] = (short)(v >> 16);
        }
    }
    __syncthreads();

    const int wave = t >> 6, lane = t & 63, quad = lane >> 4, l16 = lane & 15;
    floatx4 acc[2][2];
    #pragma unroll
    for (int i = 0; i < 2; ++i)
        #pragma unroll
        for (int j = 0; j < 2; ++j) acc[i][j] = (floatx4){0.f, 0.f, 0.f, 0.f};

    #pragma unroll
    for (int kk = 0; kk < 4; ++kk) {
        int chA = kk * 4 + quad;
        short8 a0 = *(const short8*)&Wo[(chA * 128 + wave * 32 + l16) * 8];
        short8 a1 = *(const short8*)&Wo[(chA * 128 + wave * 32 + 16 + l16) * 8];
        #pragma unroll
        for (int nt = 0; nt < 2; ++nt) {
            short8 bf = *(const short8*)&As[(nt * 16 + l16) * RSA + kk * 32 + quad * 8];
            acc[0][nt] = __builtin_amdgcn_mfma_f32_16x16x32_bf16(a0, bf, acc[0][nt], 0, 0, 0);
            acc[1][nt] = __builtin_amdgcn_mfma_f32_16x16x32_bf16(a1, bf, acc[1][nt], 0, 0, 0);
        }
    }

    #pragma unroll
    for (int mt = 0; mt < 2; ++mt)
        #pragma unroll
        for (int nt = 0; nt < 2; ++nt)
            #pragma unroll
            for (int r = 0; r < 4; ++r) {
                int co  = wave * 32 + mt * 16 + quad * 4 + r;
                int col = col0 + nt * 16 + l16;
                dout[(b * 256 + 128 + co) * 2304 + col] = acc[mt][nt][r];  // fp32 out
            }
}

// ---------------------------------------------------------------------------
extern "C" void kernel_launch(void* const* d_in, const int* in_sizes, int n_in,
                              void* d_out, int out_size, void* d_ws, size_t ws_size,
                              hipStream_t stream)
{
    const float* x  = (const float*)d_in[0];
    const float* wi = (const float*)d_in[1];
    const float* wq = (const float*)d_in[2];
    const float* wo = (const float*)d_in[3];
    float* dout = (float*)d_out;

    char* ws = (char*)d_ws;
    _Float16* qT   = (_Float16*)(ws);                   // 2,359,296 B
    _Float16* kT   = (_Float16*)(ws + 2359296);         // 2,359,296 B
    _Float16* vbuf = (_Float16*)(ws + 4718592);         // 2,359,296 B
    short* attnbuf = (short*)(ws + 7077888);            // 2,359,296 B (bf16)
    short* Wt      = (short*)(ws + 9437184);            // 1,179,648 B
    short* Wot     = (short*)(ws + 10616832);           // 32,768 B
    short* Xt      = (short*)(ws + 10649600);           // 2,359,296 B

    transform_w<<<2944, 256, 0, stream>>>(wi, wq, wo, x, Wt, Wot, Xt);
    conv_main<<<dim3(48, 4, 4), 256, 0, stream>>>(Xt, Wt, dout, qT, kT, vbuf);
    attn_kernel<<<dim3(36, 32), 256, 0, stream>>>(qT, kT, vbuf, attnbuf);
    conv1x1<<<dim3(72, 4), 256, 0, stream>>>(attnbuf, Wot, dout);
}